// Round 7
// baseline (212.704 us; speedup 1.0000x reference)
//
#include <hip/hip_runtime.h>
#include <hip/hip_bf16.h>
#include <stdint.h>

typedef __bf16 bf16x8 __attribute__((ext_vector_type(8)));
typedef __bf16 bf16x4_t __attribute__((ext_vector_type(4)));
typedef float  f32x4  __attribute__((ext_vector_type(4)));
typedef short  short8 __attribute__((ext_vector_type(8)));
typedef short  short4v __attribute__((ext_vector_type(4)));
typedef float  float4v __attribute__((ext_vector_type(4)));

#define AS1 __attribute__((address_space(1)))
#define AS3 __attribute__((address_space(3)))

__device__ __forceinline__ void g2l16(const void* g, void* l) {
    __builtin_amdgcn_global_load_lds((const AS1 void*)g, (AS3 void*)l, 16, 0, 0);
}

__device__ __forceinline__ short f2bf(float f) {
    unsigned u = __builtin_bit_cast(unsigned, f);
    unsigned r = u + 0x7FFFu + ((u >> 16) & 1u);
    return (short)(r >> 16);
}

__device__ __forceinline__ bf16x8 ldb8(const short* p) {
    return __builtin_bit_cast(bf16x8, *(const short8*)p);
}

__device__ __forceinline__ float fast_exp2(float x) {
    return __builtin_amdgcn_exp2f(x);
}

#define LOG2E 1.44269504f
#define QSCL (0.125f * LOG2E)

// ---------------- prep: cast X fp32->bf16 (blocks 0..4095) + transpose weights (4096..8191) --
__global__ __launch_bounds__(256) void prep(
    const float* __restrict__ X, short* __restrict__ Xb,
    const float* __restrict__ W0, const float* __restrict__ W1,
    const float* __restrict__ W2, const float* __restrict__ W3,
    short* __restrict__ T0, short* __restrict__ T1,
    short* __restrict__ T2, short* __restrict__ T3) {
    int gb = blockIdx.x;
    if (gb < 4096) {
        int i = (gb * 256 + threadIdx.x) * 4;
        float4v v = *(const float4v*)(X + i);
        short4v o;
        o[0] = f2bf(v[0]); o[1] = f2bf(v[1]); o[2] = f2bf(v[2]); o[3] = f2bf(v[3]);
        *(short4v*)(Xb + i) = o;
        return;
    }
    int t = gb - 4096;
    int z = t >> 10, rem = t & 1023;
    int xb = rem & 31, yb = rem >> 5;
    const float* W = z == 0 ? W0 : z == 1 ? W1 : z == 2 ? W2 : W3;
    short* T = z == 0 ? T0 : z == 1 ? T1 : z == 2 ? T2 : T3;
    __shared__ float tt[32][33];
    int n0 = xb * 32, k0 = yb * 32;
    int tx = threadIdx.x & 31, ty = threadIdx.x >> 5;
#pragma unroll
    for (int i = 0; i < 4; i++)
        tt[ty + i * 8][tx] = W[(size_t)(k0 + ty + i * 8) * 1024 + n0 + tx];
    __syncthreads();
#pragma unroll
    for (int i = 0; i < 4; i++)
        T[(size_t)(n0 + ty + i * 8) * 1024 + k0 + tx] = f2bf(tt[tx][ty + i * 8]);
}

// ---------------- fused QKV GEMM: Xb[4096][1024] @ W^T -> Qb(prescaled), Kb, VT ----------
#define VROW 136
__global__ __launch_bounds__(256) void gemm_qkv(
    const short* __restrict__ Xb,
    const short* __restrict__ WqT, const short* __restrict__ WkT, const short* __restrict__ WvT,
    const float* __restrict__ bq, const float* __restrict__ bk, const float* __restrict__ bv,
    short* __restrict__ Qb, short* __restrict__ Kb, short* __restrict__ VT) {
    const int K = 1024, N = 1024;
    int mt = blockIdx.x;
    int yy = blockIdx.y;
    int mat = yy >> 3, nt = yy & 7;
    const short* Bt = mat == 0 ? WqT : mat == 1 ? WkT : WvT;
    const float* bias = mat == 0 ? bq : mat == 1 ? bk : bv;

    int tid = threadIdx.x;
    int w = tid >> 6, lane = tid & 63;
    int quad = lane >> 4, l16 = lane & 15;
    int wy = w >> 1, wx = w & 1;

    __shared__ __align__(16) short smem[128 * VROW];
    short* A_lds = smem;
    short* B_lds = smem + 4096;

    f32x4 acc[4][4];
#pragma unroll
    for (int mi = 0; mi < 4; mi++)
#pragma unroll
        for (int ni = 0; ni < 4; ni++) acc[mi][ni] = (f32x4){0.f, 0.f, 0.f, 0.f};

    int m0 = mt * 128, n0 = nt * 128;
    for (int kt = 0; kt < 32; kt++) {
        __syncthreads();
#pragma unroll
        for (int c = 0; c < 2; c++) {
            int row = w * 32 + c * 16 + (lane >> 2);
            g2l16(Xb + (size_t)(m0 + row) * K + kt * 32 + (lane & 3) * 8,
                  &A_lds[(w * 32 + c * 16) * 32]);
            g2l16(Bt + (size_t)(n0 + row) * K + kt * 32 + (lane & 3) * 8,
                  &B_lds[(w * 32 + c * 16) * 32]);
        }
        __syncthreads();
        bf16x8 af[4], bfr[4];
#pragma unroll
        for (int i = 0; i < 4; i++) {
            af[i]  = ldb8(&A_lds[(wy * 64 + i * 16 + l16) * 32 + quad * 8]);
            bfr[i] = ldb8(&B_lds[(wx * 64 + i * 16 + l16) * 32 + quad * 8]);
        }
#pragma unroll
        for (int mi = 0; mi < 4; mi++)
#pragma unroll
            for (int ni = 0; ni < 4; ni++)
                acc[mi][ni] = __builtin_amdgcn_mfma_f32_16x16x32_bf16(af[mi], bfr[ni], acc[mi][ni], 0, 0, 0);
    }

    if (mat < 2) {
        short* Cout = mat == 0 ? Qb : Kb;
        float s = mat == 0 ? QSCL : 1.0f;
#pragma unroll
        for (int ni = 0; ni < 4; ni++) {
            int col = n0 + wx * 64 + ni * 16 + l16;
            float bv_ = bias[col];
#pragma unroll
            for (int mi = 0; mi < 4; mi++)
#pragma unroll
                for (int r = 0; r < 4; r++) {
                    int row = m0 + wy * 64 + mi * 16 + quad * 4 + r;
                    Cout[(size_t)row * N + col] = f2bf((acc[mi][ni][r] + bv_) * s);
                }
        }
    } else {
        __syncthreads();
#pragma unroll
        for (int ni = 0; ni < 4; ni++) {
            int cl = wx * 64 + ni * 16 + l16;
            float bv_ = bias[n0 + cl];
#pragma unroll
            for (int mi = 0; mi < 4; mi++) {
                int ml = wy * 64 + mi * 16 + quad * 4;
                f32x4 a = acc[mi][ni];
                f32x4 av = {a[0] + bv_, a[1] + bv_, a[2] + bv_, a[3] + bv_};
                bf16x4_t ob = __builtin_convertvector(av, bf16x4_t);
                *(short4v*)&smem[cl * VROW + ml] = __builtin_bit_cast(short4v, ob);
            }
        }
        __syncthreads();
        int bb = m0 >> 11, ss0 = m0 & 2047;
        int t16 = tid & 15, cw = tid >> 4;
#pragma unroll
        for (int p = 0; p < 8; p++) {
            int cl = p * 16 + cw;
            int col = n0 + cl;
            *(short8*)&VT[(((size_t)(bb * 16)) << 17) + (size_t)col * 2048 + ss0 + t16 * 8] =
                *(const short8*)&smem[cl * VROW + t16 * 8];
        }
    }
}

// ---------------- output GEMM: ctx[4096][1024] @ Wo^T + bo -> out fp32 (64x128 tiles) ----
__global__ __launch_bounds__(256) void gemm_out(
    const short* __restrict__ Ab, const short* __restrict__ Bt,
    const float* __restrict__ bias, float* __restrict__ C) {
    const int K = 1024, N = 1024;
    int mt = blockIdx.x, nt = blockIdx.y;
    int tid = threadIdx.x;
    int w = tid >> 6, lane = tid & 63;
    int quad = lane >> 4, l16 = lane & 15;

    __shared__ __align__(16) short A_lds[64 * 32];
    __shared__ __align__(16) short B_lds[128 * 32];

    f32x4 acc[4][2];
#pragma unroll
    for (int mi = 0; mi < 4; mi++)
#pragma unroll
        for (int ni = 0; ni < 2; ni++) acc[mi][ni] = (f32x4){0.f, 0.f, 0.f, 0.f};

    int m0 = mt * 64, n0 = nt * 128;
    for (int kt = 0; kt < 32; kt++) {
        __syncthreads();
        {
            int row = w * 16 + (lane >> 2);
            g2l16(Ab + (size_t)(m0 + row) * K + kt * 32 + (lane & 3) * 8,
                  &A_lds[(w * 16) * 32]);
        }
#pragma unroll
        for (int c = 0; c < 2; c++) {
            int row = w * 32 + c * 16 + (lane >> 2);
            g2l16(Bt + (size_t)(n0 + row) * K + kt * 32 + (lane & 3) * 8,
                  &B_lds[(w * 32 + c * 16) * 32]);
        }
        __syncthreads();
        bf16x8 af[4], bfr[2];
#pragma unroll
        for (int i = 0; i < 4; i++)
            af[i] = ldb8(&A_lds[(i * 16 + l16) * 32 + quad * 8]);
#pragma unroll
        for (int i = 0; i < 2; i++)
            bfr[i] = ldb8(&B_lds[(w * 32 + i * 16 + l16) * 32 + quad * 8]);
#pragma unroll
        for (int mi = 0; mi < 4; mi++)
#pragma unroll
            for (int ni = 0; ni < 2; ni++)
                acc[mi][ni] = __builtin_amdgcn_mfma_f32_16x16x32_bf16(af[mi], bfr[ni], acc[mi][ni], 0, 0, 0);
    }
#pragma unroll
    for (int ni = 0; ni < 2; ni++) {
        int col = n0 + w * 32 + ni * 16 + l16;
        float bv_ = bias[col];
#pragma unroll
        for (int mi = 0; mi < 4; mi++)
#pragma unroll
            for (int r = 0; r < 4; r++) {
                int row = m0 + mi * 16 + quad * 4 + r;
                C[(size_t)row * N + col] = acc[mi][ni][r] + bv_;
            }
    }
}

// ---------------- flash attention v6: Tq=128, Tk=128, 512 thr, no-max, XCD swizzle ----------
// Half the barriers of Tk=64 (K/V staging is the only cross-wave sync; P is per-wave).
#define PROW 144   // per-wave P buffer: 16 q rows x 2 halves x 72 shorts
__global__ __launch_bounds__(512) void attn_kernel(
    const short* __restrict__ Qb, const short* __restrict__ Kb,
    const short* __restrict__ VT, const float* __restrict__ mask,
    short* __restrict__ ctx) {
    const int S = 2048, E = 1024, HH = 16;
    int g = blockIdx.x;                 // 0..511
    int p = (g & 7) + 8 * (g >> 7);     // 0..31 = b*16+h
    int qb = (g >> 3) & 15;             // 0..15
    int b = p >> 4, h = p & 15;

    int tid = threadIdx.x;
    int w = tid >> 6, lane = tid & 63;
    int quad = lane >> 4, l16 = lane & 15;

    __shared__ __align__(16) short K_lds[128 * 64];    // [k=128][d=64], 16B-blk swizzled
    __shared__ __align__(16) short VT_lds[64 * 128];   // [d=64][k=128], 16B-blk swizzled
    __shared__ __align__(16) short P_lds[8][16 * PROW];
    __shared__ int maskflag;

    if (tid == 0) maskflag = 1;
    __syncthreads();
    {
        float4v m = *(const float4v*)(mask + b * S + tid * 4);
        if (!(m[0] == 1.f && m[1] == 1.f && m[2] == 1.f && m[3] == 1.f))
            maskflag = 0;
    }
    __syncthreads();
    const bool nomask = (maskflag != 0);

    int q0 = qb * 128;

    bf16x8 qf[2];
#pragma unroll
    for (int kc = 0; kc < 2; kc++)
        qf[kc] = ldb8(Qb + (size_t)(b * S + q0 + w * 16 + l16) * E + h * 64 + kc * 32 + quad * 8);

    f32x4 O_t[4];
    float lsum = 0.f;
#pragma unroll
    for (int nd = 0; nd < 4; nd++) O_t[nd] = (f32x4){0.f, 0.f, 0.f, 0.f};

    const short* Kbase = Kb + (size_t)b * S * E + h * 64;
    const short* Vbase = VT + (size_t)(b * HH + h) * 64 * S;
    short* Pw = &P_lds[w][0];
    int rsw = l16 & 7;

    for (int kt = 0; kt < 16; kt++) {
        int k0 = kt * 128;
        __syncthreads();
        // K: 128 rows x 64 d. wave stages 16 rows via 2 calls (8 rows each).
#pragma unroll
        for (int c = 0; c < 2; c++) {
            int row = w * 16 + c * 8 + (lane >> 3);
            int srcb = (lane & 7) ^ (row & 7);
            g2l16(Kbase + (size_t)(k0 + row) * E + srcb * 8, &K_lds[(w * 16 + c * 8) * 64]);
        }
        // V^T: 64 rows x 128 k. wave stages 8 rows via 2 calls (4 rows each).
#pragma unroll
        for (int c = 0; c < 2; c++) {
            int rowd = w * 8 + c * 4 + (lane >> 4);
            int srcb = (lane & 15) ^ (rowd & 7);
            g2l16(Vbase + (size_t)rowd * S + k0 + srcb * 8, &VT_lds[(w * 8 + c * 4) * 128]);
        }
        __syncthreads();

        // S^T = K·Q^T : sc[ni] rows k = ni*16+quad*4+r, cols q = l16
        f32x4 sc[8];
#pragma unroll
        for (int ni = 0; ni < 8; ni++) sc[ni] = (f32x4){0.f, 0.f, 0.f, 0.f};
#pragma unroll
        for (int ni = 0; ni < 8; ni++) {
#pragma unroll
            for (int kc = 0; kc < 2; kc++) {
                int blk = (kc * 4 + quad) ^ rsw;
                bf16x8 kf = ldb8(&K_lds[(ni * 16 + l16) * 64 + blk * 8]);
                sc[ni] = __builtin_amdgcn_mfma_f32_16x16x32_bf16(kf, qf[kc], sc[ni], 0, 0, 0);
            }
        }

        if (!nomask) {
#pragma unroll
            for (int ni = 0; ni < 8; ni++) {
                float4v mrow = *(const float4v*)(mask + b * S + k0 + ni * 16 + quad * 4);
#pragma unroll
                for (int r = 0; r < 4; r++)
                    sc[ni][r] += (1.0f - mrow[r]) * (-10000.0f * LOG2E);
            }
        }

#pragma unroll
        for (int ni = 0; ni < 8; ni++)
#pragma unroll
            for (int r = 0; r < 4; r++) {
                float pp = fast_exp2(sc[ni][r]);
                sc[ni][r] = pp;
                lsum += pp;
            }

        // P write: half hh at offset hh*72; lane -> [q=l16][k-local=(ni&3)*16+quad*4]
#pragma unroll
        for (int ni = 0; ni < 8; ni++) {
            bf16x4_t pb = __builtin_convertvector(sc[ni], bf16x4_t);
            *(short4v*)&Pw[l16 * PROW + (ni >> 2) * 72 + (ni & 3) * 16 + quad * 4] =
                __builtin_bit_cast(short4v, pb);
        }

        // O^T += V^T · P^T, two 64-k halves (per-wave, no barrier)
#pragma unroll
        for (int hh = 0; hh < 2; hh++) {
#pragma unroll
            for (int ks = 0; ks < 2; ks++) {
                bf16x8 pf = ldb8(&Pw[l16 * PROW + hh * 72 + ks * 32 + quad * 8]);
#pragma unroll
                for (int nd = 0; nd < 4; nd++) {
                    int blk = hh * 8 + ((ks * 4 + quad) ^ rsw);
                    bf16x8 vf = ldb8(&VT_lds[(nd * 16 + l16) * 128 + blk * 8]);
                    O_t[nd] = __builtin_amdgcn_mfma_f32_16x16x32_bf16(vf, pf, O_t[nd], 0, 0, 0);
                }
            }
        }
    }

    {
        float l = lsum;
        l += __shfl_xor(l, 16, 64);
        l += __shfl_xor(l, 32, 64);
        float inv = l > 0.f ? 1.0f / l : 0.f;
        int row = q0 + w * 16 + l16;
#pragma unroll
        for (int nd = 0; nd < 4; nd++) {
            f32x4 o = O_t[nd];
            f32x4 os = {o[0] * inv, o[1] * inv, o[2] * inv, o[3] * inv};
            bf16x4_t ob = __builtin_convertvector(os, bf16x4_t);
            *(short4v*)&ctx[(size_t)(b * S + row) * E + h * 64 + nd * 16 + quad * 4] =
                __builtin_bit_cast(short4v, ob);
        }
    }
}

extern "C" void kernel_launch(void* const* d_in, const int* in_sizes, int n_in,
                              void* d_out, int out_size, void* d_ws, size_t ws_size,
                              hipStream_t stream) {
    const float* X    = (const float*)d_in[0];
    const float* mask = (const float*)d_in[1];
    const float* Wq   = (const float*)d_in[2];
    const float* bq   = (const float*)d_in[3];
    const float* Wk   = (const float*)d_in[4];
    const float* bk   = (const float*)d_in[5];
    const float* Wv   = (const float*)d_in[6];
    const float* bv   = (const float*)d_in[7];
    const float* Wo   = (const float*)d_in[8];
    const float* bo   = (const float*)d_in[9];
    float* out = (float*)d_out;

    char* ws = (char*)d_ws;
    short* Xb  = (short*)(ws);                     // 8 MiB (reused as ctx)
    short* WqT = (short*)(ws + (8u << 20));        // 2 MiB
    short* WkT = (short*)(ws + (10u << 20));
    short* WvT = (short*)(ws + (12u << 20));
    short* WoT = (short*)(ws + (14u << 20));
    short* Qb  = (short*)(ws + (16u << 20));       // 8 MiB
    short* Kb  = (short*)(ws + (24u << 20));       // 8 MiB
    short* VT  = (short*)(ws + (32u << 20));       // 8 MiB, V stored transposed [bh][64][2048]
    short* ctx = Xb;

    prep<<<8192, 256, 0, stream>>>(X, Xb, Wq, Wk, Wv, Wo, WqT, WkT, WvT, WoT);
    gemm_qkv<<<dim3(32, 24), 256, 0, stream>>>(Xb, WqT, WkT, WvT, bq, bk, bv, Qb, Kb, VT);
    attn_kernel<<<512, 512, 0, stream>>>(Qb, Kb, VT, mask, ctx);
    gemm_out<<<dim3(64, 8), 256, 0, stream>>>(ctx, WoT, bo, out);
}

// Round 8
// 194.038 us; speedup vs baseline: 1.0962x; 1.0962x over previous
//
#include <hip/hip_runtime.h>
#include <hip/hip_bf16.h>
#include <stdint.h>

typedef __bf16 bf16x8 __attribute__((ext_vector_type(8)));
typedef __bf16 bf16x4_t __attribute__((ext_vector_type(4)));
typedef float  f32x4  __attribute__((ext_vector_type(4)));
typedef short  short8 __attribute__((ext_vector_type(8)));
typedef short  short4v __attribute__((ext_vector_type(4)));
typedef float  float4v __attribute__((ext_vector_type(4)));

#define AS1 __attribute__((address_space(1)))
#define AS3 __attribute__((address_space(3)))

__device__ __forceinline__ void g2l16(const void* g, void* l) {
    __builtin_amdgcn_global_load_lds((const AS1 void*)g, (AS3 void*)l, 16, 0, 0);
}

__device__ __forceinline__ short f2bf(float f) {
    unsigned u = __builtin_bit_cast(unsigned, f);
    unsigned r = u + 0x7FFFu + ((u >> 16) & 1u);
    return (short)(r >> 16);
}

__device__ __forceinline__ bf16x8 ldb8(const short* p) {
    return __builtin_bit_cast(bf16x8, *(const short8*)p);
}

__device__ __forceinline__ float fast_exp2(float x) {
    return __builtin_amdgcn_exp2f(x);
}

#define LOG2E 1.44269504f
#define QSCL (0.125f * LOG2E)

// ---------------- prep: cast X fp32->bf16 (blocks 0..4095) + transpose weights (4096..8191) --
__global__ __launch_bounds__(256) void prep(
    const float* __restrict__ X, short* __restrict__ Xb,
    const float* __restrict__ W0, const float* __restrict__ W1,
    const float* __restrict__ W2, const float* __restrict__ W3,
    short* __restrict__ T0, short* __restrict__ T1,
    short* __restrict__ T2, short* __restrict__ T3) {
    int gb = blockIdx.x;
    if (gb < 4096) {
        int i = (gb * 256 + threadIdx.x) * 4;
        float4v v = *(const float4v*)(X + i);
        short4v o;
        o[0] = f2bf(v[0]); o[1] = f2bf(v[1]); o[2] = f2bf(v[2]); o[3] = f2bf(v[3]);
        *(short4v*)(Xb + i) = o;
        return;
    }
    int t = gb - 4096;
    int z = t >> 10, rem = t & 1023;
    int xb = rem & 31, yb = rem >> 5;
    const float* W = z == 0 ? W0 : z == 1 ? W1 : z == 2 ? W2 : W3;
    short* T = z == 0 ? T0 : z == 1 ? T1 : z == 2 ? T2 : T3;
    __shared__ float tt[32][33];
    int n0 = xb * 32, k0 = yb * 32;
    int tx = threadIdx.x & 31, ty = threadIdx.x >> 5;
#pragma unroll
    for (int i = 0; i < 4; i++)
        tt[ty + i * 8][tx] = W[(size_t)(k0 + ty + i * 8) * 1024 + n0 + tx];
    __syncthreads();
#pragma unroll
    for (int i = 0; i < 4; i++)
        T[(size_t)(n0 + ty + i * 8) * 1024 + k0 + tx] = f2bf(tt[tx][ty + i * 8]);
}

// ---------------- fused QKV GEMM: Xb[4096][1024] @ W^T -> Qb(prescaled), Kb, VT ----------
// Q/K path: operand-swapped MFMA (C^T in regs: lane holds 4 consecutive out-cols at
// fixed row) -> direct short4 stores. V path: original order + LDS transpose stage.
#define VROW 136
__global__ __launch_bounds__(256) void gemm_qkv(
    const short* __restrict__ Xb,
    const short* __restrict__ WqT, const short* __restrict__ WkT, const short* __restrict__ WvT,
    const float* __restrict__ bq, const float* __restrict__ bk, const float* __restrict__ bv,
    short* __restrict__ Qb, short* __restrict__ Kb, short* __restrict__ VT) {
    const int K = 1024, N = 1024;
    int mt = blockIdx.x;
    int yy = blockIdx.y;
    int mat = yy >> 3, nt = yy & 7;
    const short* Bt = mat == 0 ? WqT : mat == 1 ? WkT : WvT;
    const float* bias = mat == 0 ? bq : mat == 1 ? bk : bv;

    int tid = threadIdx.x;
    int w = tid >> 6, lane = tid & 63;
    int quad = lane >> 4, l16 = lane & 15;
    int wy = w >> 1, wx = w & 1;

    __shared__ __align__(16) short smem[128 * VROW];
    short* A_lds = smem;
    short* B_lds = smem + 4096;

    f32x4 acc[4][4];
#pragma unroll
    for (int i = 0; i < 4; i++)
#pragma unroll
        for (int j = 0; j < 4; j++) acc[i][j] = (f32x4){0.f, 0.f, 0.f, 0.f};

    int m0 = mt * 128, n0 = nt * 128;

    if (mat < 2) {
        // ---- Q/K: swapped operands -> C^T ----
        for (int kt = 0; kt < 32; kt++) {
            __syncthreads();
#pragma unroll
            for (int c = 0; c < 2; c++) {
                int row = w * 32 + c * 16 + (lane >> 2);
                g2l16(Xb + (size_t)(m0 + row) * K + kt * 32 + (lane & 3) * 8,
                      &A_lds[(w * 32 + c * 16) * 32]);
                g2l16(Bt + (size_t)(n0 + row) * K + kt * 32 + (lane & 3) * 8,
                      &B_lds[(w * 32 + c * 16) * 32]);
            }
            __syncthreads();
            bf16x8 af[4], bfr[4];
#pragma unroll
            for (int i = 0; i < 4; i++) {
                af[i]  = ldb8(&A_lds[(wy * 64 + i * 16 + l16) * 32 + quad * 8]);
                bfr[i] = ldb8(&B_lds[(wx * 64 + i * 16 + l16) * 32 + quad * 8]);
            }
#pragma unroll
            for (int ni = 0; ni < 4; ni++)
#pragma unroll
                for (int mi = 0; mi < 4; mi++)
                    acc[ni][mi] = __builtin_amdgcn_mfma_f32_16x16x32_bf16(bfr[ni], af[mi], acc[ni][mi], 0, 0, 0);
        }
        short* Cout = mat == 0 ? Qb : Kb;
        float s = mat == 0 ? QSCL : 1.0f;
#pragma unroll
        for (int ni = 0; ni < 4; ni++) {
            int c0 = n0 + wx * 64 + ni * 16 + quad * 4;
            float4v bv4 = *(const float4v*)(bias + c0);
#pragma unroll
            for (int mi = 0; mi < 4; mi++) {
                int row = m0 + wy * 64 + mi * 16 + l16;
                f32x4 a = acc[ni][mi];
                f32x4 av = {(a[0] + bv4[0]) * s, (a[1] + bv4[1]) * s,
                            (a[2] + bv4[2]) * s, (a[3] + bv4[3]) * s};
                bf16x4_t ob = __builtin_convertvector(av, bf16x4_t);
                *(short4v*)&Cout[(size_t)row * N + c0] = __builtin_bit_cast(short4v, ob);
            }
        }
    } else {
        // ---- V: original order, LDS transpose stage, coalesced VT write ----
        for (int kt = 0; kt < 32; kt++) {
            __syncthreads();
#pragma unroll
            for (int c = 0; c < 2; c++) {
                int row = w * 32 + c * 16 + (lane >> 2);
                g2l16(Xb + (size_t)(m0 + row) * K + kt * 32 + (lane & 3) * 8,
                      &A_lds[(w * 32 + c * 16) * 32]);
                g2l16(Bt + (size_t)(n0 + row) * K + kt * 32 + (lane & 3) * 8,
                      &B_lds[(w * 32 + c * 16) * 32]);
            }
            __syncthreads();
            bf16x8 af[4], bfr[4];
#pragma unroll
            for (int i = 0; i < 4; i++) {
                af[i]  = ldb8(&A_lds[(wy * 64 + i * 16 + l16) * 32 + quad * 8]);
                bfr[i] = ldb8(&B_lds[(wx * 64 + i * 16 + l16) * 32 + quad * 8]);
            }
#pragma unroll
            for (int mi = 0; mi < 4; mi++)
#pragma unroll
                for (int ni = 0; ni < 4; ni++)
                    acc[mi][ni] = __builtin_amdgcn_mfma_f32_16x16x32_bf16(af[mi], bfr[ni], acc[mi][ni], 0, 0, 0);
        }
        __syncthreads();
#pragma unroll
        for (int ni = 0; ni < 4; ni++) {
            int cl = wx * 64 + ni * 16 + l16;
            float bv_ = bias[n0 + cl];
#pragma unroll
            for (int mi = 0; mi < 4; mi++) {
                int ml = wy * 64 + mi * 16 + quad * 4;
                f32x4 a = acc[mi][ni];
                f32x4 av = {a[0] + bv_, a[1] + bv_, a[2] + bv_, a[3] + bv_};
                bf16x4_t ob = __builtin_convertvector(av, bf16x4_t);
                *(short4v*)&smem[cl * VROW + ml] = __builtin_bit_cast(short4v, ob);
            }
        }
        __syncthreads();
        int bb = m0 >> 11, ss0 = m0 & 2047;
        int t16 = tid & 15, cw = tid >> 4;
#pragma unroll
        for (int p = 0; p < 8; p++) {
            int cl = p * 16 + cw;
            int col = n0 + cl;
            *(short8*)&VT[(((size_t)(bb * 16)) << 17) + (size_t)col * 2048 + ss0 + t16 * 8] =
                *(const short8*)&smem[cl * VROW + t16 * 8];
        }
    }
}

// ---------------- output GEMM: ctx @ Wo^T + bo -> out fp32, C^T regs, float4 stores ----
__global__ __launch_bounds__(256) void gemm_out(
    const short* __restrict__ Ab, const short* __restrict__ Bt,
    const float* __restrict__ bias, float* __restrict__ C) {
    const int K = 1024, N = 1024;
    int mt = blockIdx.x, nt = blockIdx.y;
    int tid = threadIdx.x;
    int w = tid >> 6, lane = tid & 63;
    int quad = lane >> 4, l16 = lane & 15;

    __shared__ __align__(16) short A_lds[64 * 32];
    __shared__ __align__(16) short B_lds[128 * 32];

    f32x4 acc[2][4];
#pragma unroll
    for (int ni = 0; ni < 2; ni++)
#pragma unroll
        for (int mi = 0; mi < 4; mi++) acc[ni][mi] = (f32x4){0.f, 0.f, 0.f, 0.f};

    int m0 = mt * 64, n0 = nt * 128;
    for (int kt = 0; kt < 32; kt++) {
        __syncthreads();
        {
            int row = w * 16 + (lane >> 2);
            g2l16(Ab + (size_t)(m0 + row) * K + kt * 32 + (lane & 3) * 8,
                  &A_lds[(w * 16) * 32]);
        }
#pragma unroll
        for (int c = 0; c < 2; c++) {
            int row = w * 32 + c * 16 + (lane >> 2);
            g2l16(Bt + (size_t)(n0 + row) * K + kt * 32 + (lane & 3) * 8,
                  &B_lds[(w * 32 + c * 16) * 32]);
        }
        __syncthreads();
        bf16x8 af[4], bfr[2];
#pragma unroll
        for (int i = 0; i < 4; i++)
            af[i] = ldb8(&A_lds[(i * 16 + l16) * 32 + quad * 8]);
#pragma unroll
        for (int i = 0; i < 2; i++)
            bfr[i] = ldb8(&B_lds[(w * 32 + i * 16 + l16) * 32 + quad * 8]);
#pragma unroll
        for (int ni = 0; ni < 2; ni++)
#pragma unroll
            for (int mi = 0; mi < 4; mi++)
                acc[ni][mi] = __builtin_amdgcn_mfma_f32_16x16x32_bf16(bfr[ni], af[mi], acc[ni][mi], 0, 0, 0);
    }
#pragma unroll
    for (int ni = 0; ni < 2; ni++) {
        int c0 = n0 + w * 32 + ni * 16 + quad * 4;
        float4v bv4 = *(const float4v*)(bias + c0);
#pragma unroll
        for (int mi = 0; mi < 4; mi++) {
            int row = m0 + mi * 16 + l16;
            f32x4 a = acc[ni][mi];
            float4v av = {a[0] + bv4[0], a[1] + bv4[1], a[2] + bv4[2], a[3] + bv4[3]};
            *(float4v*)&C[(size_t)row * N + c0] = av;
        }
    }
}

// ---------------- flash attention v7: Tk=64, 512 thr, dbuf K/V (1 barrier/iter),
// no-max softmax, lsum via ones-MFMA, XCD swizzle ----------
#define PROW 72
__global__ __launch_bounds__(512) void attn_kernel(
    const short* __restrict__ Qb, const short* __restrict__ Kb,
    const short* __restrict__ VT, const float* __restrict__ mask,
    short* __restrict__ ctx) {
    const int S = 2048, E = 1024, HH = 16;
    int g = blockIdx.x;                 // 0..511
    int p = (g & 7) + 8 * (g >> 7);     // 0..31 = b*16+h
    int qb = (g >> 3) & 15;             // 0..15
    int b = p >> 4, h = p & 15;

    int tid = threadIdx.x;
    int w = tid >> 6, lane = tid & 63;
    int quad = lane >> 4, l16 = lane & 15;

    __shared__ __align__(16) short K_lds[2][64 * 64];
    __shared__ __align__(16) short VT_lds[2][64 * 64];
    __shared__ __align__(16) short P_lds[8][16 * PROW];
    __shared__ int maskflag;

    if (tid == 0) maskflag = 1;
    __syncthreads();
    {
        float4v m = *(const float4v*)(mask + b * S + tid * 4);
        if (!(m[0] == 1.f && m[1] == 1.f && m[2] == 1.f && m[3] == 1.f))
            maskflag = 0;
    }
    __syncthreads();
    const bool nomask = (maskflag != 0);

    int q0 = qb * 128;

    bf16x8 qf[2];
#pragma unroll
    for (int kc = 0; kc < 2; kc++)
        qf[kc] = ldb8(Qb + (size_t)(b * S + q0 + w * 16 + l16) * E + h * 64 + kc * 32 + quad * 8);

    // all-ones A fragment for the lsum MFMA
    short8 ones_s = {0x3F80, 0x3F80, 0x3F80, 0x3F80, 0x3F80, 0x3F80, 0x3F80, 0x3F80};
    bf16x8 vones = __builtin_bit_cast(bf16x8, ones_s);

    f32x4 O_t[4];
    f32x4 lacc = (f32x4){0.f, 0.f, 0.f, 0.f};
#pragma unroll
    for (int nd = 0; nd < 4; nd++) O_t[nd] = (f32x4){0.f, 0.f, 0.f, 0.f};

    const short* Kbase = Kb + (size_t)b * S * E + h * 64;
    const short* Vbase = VT + (size_t)(b * HH + h) * 64 * S;
    short* Pw = &P_lds[w][0];
    int rsw = l16 & 7;

    int srow = w * 8 + (lane >> 3);
    int ssrcb = (lane & 7) ^ (srow & 7);

    // stage tile 0 into buf 0
    g2l16(Kbase + (size_t)srow * E + ssrcb * 8, &K_lds[0][(w * 8) * 64]);
    g2l16(Vbase + (size_t)srow * S + 0 + ssrcb * 8, &VT_lds[0][(w * 8) * 64]);
    __syncthreads();

    for (int kt = 0; kt < 32; kt++) {
        int cur = kt & 1;
        int k0 = kt * 64;
        // prefetch next tile into the other buffer (async; drained by the barrier below)
        if (kt < 31) {
            int k1 = k0 + 64;
            g2l16(Kbase + (size_t)(k1 + srow) * E + ssrcb * 8, &K_lds[cur ^ 1][(w * 8) * 64]);
            g2l16(Vbase + (size_t)srow * S + k1 + ssrcb * 8, &VT_lds[cur ^ 1][(w * 8) * 64]);
        }
        const short* Kl = &K_lds[cur][0];
        const short* Vl = &VT_lds[cur][0];

        // S^T = K·Q^T : sc[ni] rows k = ni*16+quad*4+r, cols q = l16
        f32x4 sc[4];
#pragma unroll
        for (int ni = 0; ni < 4; ni++) sc[ni] = (f32x4){0.f, 0.f, 0.f, 0.f};
#pragma unroll
        for (int ni = 0; ni < 4; ni++) {
#pragma unroll
            for (int kc = 0; kc < 2; kc++) {
                int blk = (kc * 4 + quad) ^ rsw;
                bf16x8 kf = ldb8(&Kl[(ni * 16 + l16) * 64 + blk * 8]);
                sc[ni] = __builtin_amdgcn_mfma_f32_16x16x32_bf16(kf, qf[kc], sc[ni], 0, 0, 0);
            }
        }

        if (!nomask) {
#pragma unroll
            for (int ni = 0; ni < 4; ni++) {
                float4v mrow = *(const float4v*)(mask + b * S + k0 + ni * 16 + quad * 4);
#pragma unroll
                for (int r = 0; r < 4; r++)
                    sc[ni][r] += (1.0f - mrow[r]) * (-10000.0f * LOG2E);
            }
        }

#pragma unroll
        for (int ni = 0; ni < 4; ni++)
#pragma unroll
            for (int r = 0; r < 4; r++)
                sc[ni][r] = fast_exp2(sc[ni][r]);

#pragma unroll
        for (int ni = 0; ni < 4; ni++) {
            bf16x4_t pb = __builtin_convertvector(sc[ni], bf16x4_t);
            *(short4v*)&Pw[l16 * PROW + ni * 16 + quad * 4] =
                __builtin_bit_cast(short4v, pb);
        }

        // O^T += V^T · P^T ; lsum via ones-row MFMA
#pragma unroll
        for (int ks = 0; ks < 2; ks++) {
            bf16x8 pf = ldb8(&Pw[l16 * PROW + ks * 32 + quad * 8]);
            lacc = __builtin_amdgcn_mfma_f32_16x16x32_bf16(vones, pf, lacc, 0, 0, 0);
#pragma unroll
            for (int nd = 0; nd < 4; nd++) {
                int blk = (ks * 4 + quad) ^ rsw;
                bf16x8 vf = ldb8(&Vl[(nd * 16 + l16) * 64 + blk * 8]);
                O_t[nd] = __builtin_amdgcn_mfma_f32_16x16x32_bf16(vf, pf, O_t[nd], 0, 0, 0);
            }
        }
        __syncthreads();
    }

    {
        float l = lacc[0];   // every row of the ones-MFMA result = sum over k for q=l16
        float inv = l > 0.f ? 1.0f / l : 0.f;
        int row = q0 + w * 16 + l16;
#pragma unroll
        for (int nd = 0; nd < 4; nd++) {
            f32x4 o = O_t[nd];
            f32x4 os = {o[0] * inv, o[1] * inv, o[2] * inv, o[3] * inv};
            bf16x4_t ob = __builtin_convertvector(os, bf16x4_t);
            *(short4v*)&ctx[(size_t)(b * S + row) * E + h * 64 + nd * 16 + quad * 4] =
                __builtin_bit_cast(short4v, ob);
        }
    }
}

extern "C" void kernel_launch(void* const* d_in, const int* in_sizes, int n_in,
                              void* d_out, int out_size, void* d_ws, size_t ws_size,
                              hipStream_t stream) {
    const float* X    = (const float*)d_in[0];
    const float* mask = (const float*)d_in[1];
    const float* Wq   = (const float*)d_in[2];
    const float* bq   = (const float*)d_in[3];
    const float* Wk   = (const float*)d_in[4];
    const float* bk   = (const float*)d_in[5];
    const float* Wv   = (const float*)d_in[6];
    const float* bv   = (const float*)d_in[7];
    const float* Wo   = (const float*)d_in[8];
    const float* bo   = (const float*)d_in[9];
    float* out = (float*)d_out;

    char* ws = (char*)d_ws;
    short* Xb  = (short*)(ws);                     // 8 MiB (reused as ctx)
    short* WqT = (short*)(ws + (8u << 20));        // 2 MiB
    short* WkT = (short*)(ws + (10u << 20));
    short* WvT = (short*)(ws + (12u << 20));
    short* WoT = (short*)(ws + (14u << 20));
    short* Qb  = (short*)(ws + (16u << 20));       // 8 MiB
    short* Kb  = (short*)(ws + (24u << 20));       // 8 MiB
    short* VT  = (short*)(ws + (32u << 20));       // 8 MiB, V stored transposed [bh][64][2048]
    short* ctx = Xb;

    prep<<<8192, 256, 0, stream>>>(X, Xb, Wq, Wk, Wv, Wo, WqT, WkT, WvT, WoT);
    gemm_qkv<<<dim3(32, 24), 256, 0, stream>>>(Xb, WqT, WkT, WvT, bq, bk, bv, Qb, Kb, VT);
    attn_kernel<<<512, 512, 0, stream>>>(Qb, Kb, VT, mask, ctx);
    gemm_out<<<dim3(64, 8), 256, 0, stream>>>(ctx, WoT, bo, out);
}